// Round 6
// baseline (469.115 us; speedup 1.0000x reference)
//
#include <hip/hip_runtime.h>
#include <hip/hip_bf16.h>

// Problem constants (B=32, N=256, K=8, D=1024, OUT=1024, HID=2048)
#define ROWS   8192      // B*N
#define DIM    1024      // D
#define XCOLS  3072      // 3*D
#define OUTC   1024
#define HIDC   2048
#define EPS    1e-5f

typedef __attribute__((ext_vector_type(8))) short bf16x8;   // 8 bf16 (4 VGPRs)
typedef __attribute__((ext_vector_type(4))) float f32x4;

#define GLOBAL_AS __attribute__((address_space(1)))
#define LDS_AS    __attribute__((address_space(3)))

__device__ __forceinline__ void gll16(const void* g, void* l) {
    // async global->LDS, 16B per lane; LDS dest = wave-uniform base + lane*16
    __builtin_amdgcn_global_load_lds((const GLOBAL_AS void*)g, (LDS_AS void*)l, 16, 0, 0);
}

__device__ __forceinline__ short f2b(float f) {
    __hip_bfloat16 h = __float2bfloat16(f);
    return *reinterpret_cast<short*>(&h);
}
__device__ __forceinline__ float b2f(short s) {
    unsigned u = ((unsigned)(unsigned short)s) << 16;
    return __uint_as_float(u);
}

// ---------------------------------------------------------------------------
// Stage 1: x[r, 0:1024] = self[r, :]; x[r, 1024:3072] = mean_k(nb[r,k,:]*mask[r,k])
// ---------------------------------------------------------------------------
__global__ __launch_bounds__(256) void build_x(
    const float* __restrict__ selfv, const float* __restrict__ nb,
    const float* __restrict__ mask, __hip_bfloat16* __restrict__ xb)
{
    int r = blockIdx.x;
    int tid = threadIdx.x;
    __shared__ float ms[8];
    if (tid < 8) ms[tid] = mask[r * 8 + tid];
    __syncthreads();

    __hip_bfloat16* xr = xb + (size_t)r * XCOLS;

    {
        float4 v = ((const float4*)(selfv + (size_t)r * DIM))[tid];
        short4 o;
        o.x = f2b(v.x); o.y = f2b(v.y); o.z = f2b(v.z); o.w = f2b(v.w);
        *(short4*)&xr[tid * 4] = o;
    }

    const float4* nbase = (const float4*)(nb + (size_t)r * 8 * 2048);
#pragma unroll
    for (int half = 0; half < 2; ++half) {
        int c4 = half * 256 + tid;
        float4 acc = make_float4(0.f, 0.f, 0.f, 0.f);
#pragma unroll
        for (int k = 0; k < 8; ++k) {
            float4 t = nbase[k * 512 + c4];
            float m = ms[k];
            acc.x += t.x * m; acc.y += t.y * m; acc.z += t.z * m; acc.w += t.w * m;
        }
        short4 o;
        o.x = f2b(acc.x * 0.125f); o.y = f2b(acc.y * 0.125f);
        o.z = f2b(acc.z * 0.125f); o.w = f2b(acc.w * 0.125f);
        *(short4*)&xr[1024 + c4 * 4] = o;
    }
}

// ---------------------------------------------------------------------------
// Weight transpose + bf16 cast: W[K][N] f32 -> Wt[N][K] bf16
// ---------------------------------------------------------------------------
__global__ __launch_bounds__(256) void wtrans(
    const float* __restrict__ W, __hip_bfloat16* __restrict__ Wt, int K, int N)
{
    __shared__ float t[32][33];
    int n0 = blockIdx.x << 5, k0 = blockIdx.y << 5;
    int tx = threadIdx.x & 31, ty = threadIdx.x >> 5;
#pragma unroll
    for (int i = 0; i < 4; ++i)
        t[ty + i * 8][tx] = W[(size_t)(k0 + ty + i * 8) * N + n0 + tx];
    __syncthreads();
#pragma unroll
    for (int i = 0; i < 4; ++i) {
        int n = ty + i * 8;
        Wt[(size_t)(n0 + n) * K + k0 + tx] = __float2bfloat16(t[tx][n]);
    }
}

// ---------------------------------------------------------------------------
// 256-wide GEMM: C[M,N] = A[M,K] @ Bt[N,K]^T + bias  (bf16 in, f32 acc)
// BM=256, BN=256/128 (templated), BK=32. 512 threads = 8 waves (2M x 4N);
// per-wave output 128 x BN/4. 3 LDS buffers; tile t+2 staged while tile t
// computes; ONE counted vmcnt(TL) per tile (never 0 in main loop): after it
// + barrier, tile t+1 is fully landed for all waves while t+2 flies.
// Two phases per tile, each {stage || ds_read || 16(8) MFMA in setprio}.
// LDS chunk XOR-swizzle (c ^= (row>>1)&3), applied on BOTH the global source
// of global_load_lds and the ds_read address (same involution) ->
// ds_read_b128 bank aliasing drops 8-way -> 2-way (free).
// STATS: per-block-row column partials (sum,sumsq incl. bias) -> pS/pS2[bm][col]
// ---------------------------------------------------------------------------
template <int BN, int OUT_BF16, int STATS>
__global__ __launch_bounds__(512) void gemm256(
    const short* __restrict__ A, const short* __restrict__ Bt,
    const float* __restrict__ bias, void* __restrict__ Cout,
    float* __restrict__ pS, float* __restrict__ pS2,
    int M, int N, int K)
{
    constexpr int NW = BN / 4;          // per-wave cols: 64 or 32
    constexpr int NREP = NW / 16;       // 4 or 2
    constexpr int H = NREP / 2;         // frags per phase: 2 or 1
    constexpr int BLOADS = BN / 128;    // B gll16 per thread per tile: 2 or 1
    constexpr int TL = 2 + BLOADS;      // total gll16 per thread per tile

    __shared__ short As[3][256 * 32];   // 3 x 16 KB
    __shared__ short Bs[3][BN * 32];    // 3 x 16/8 KB

    int tid = threadIdx.x;
    int lane = tid & 63;
    int w = tid >> 6;                   // 0..7
    int wm = w >> 2, wn = w & 3;        // 2 x 4 wave grid

    // XCD swizzle (grid = 256, %8 == 0)
    int nwg = gridDim.x;
    int bid = blockIdx.x;
    int swz = (bid & 7) * (nwg >> 3) + (bid >> 3);
    int nbn = N / BN;
    int bm = swz / nbn, bn = swz % nbn;
    int brow = bm << 8, bcol = bn * BN;

    f32x4 acc[8][NREP] = {};

    // global sources, chunk-swizzled: slot s -> row s>>2, phys chunk s&3 holds
    // global chunk (s&3)^((s>>3)&3)   [(row>>1)&3 == (s>>3)&3]
    const short* gA[2];
#pragma unroll
    for (int i = 0; i < 2; ++i) {
        int s = tid + (i << 9);
        gA[i] = A + (size_t)(brow + (s >> 2)) * K + (((s & 3) ^ ((s >> 3) & 3)) << 3);
    }
    const short* gB[2];
#pragma unroll
    for (int i = 0; i < 2; ++i) {
        if (i < BLOADS) {
            int s = tid + (i << 9);
            gB[i] = Bt + (size_t)(bcol + (s >> 2)) * K + (((s & 3) ^ ((s >> 3) & 3)) << 3);
        }
    }

#define STAGE_A(buf, kk)                                        \
    do {                                                        \
        gll16(gA[0] + (kk), &As[buf][(w << 9)]);                \
        gll16(gA[1] + (kk), &As[buf][(w << 9) + 4096]);         \
    } while (0)
#define STAGE_B(buf, kk)                                        \
    do {                                                        \
        gll16(gB[0] + (kk), &Bs[buf][(w << 9)]);                \
        if constexpr (BLOADS == 2)                              \
            gll16(gB[1] + (kk), &Bs[buf][(w << 9) + 4096]);     \
    } while (0)

    // fragment read addressing (swizzled chunk is lane-constant across m,n:
    // (row>>1)&3 == ((lane&15)>>1)&3 since all row-block offsets are %4==0)
    int rA = (wm << 7) + (lane & 15);                       // local A row
    int rB = wn * NW + (lane & 15);                         // local B row
    int cswz = (((lane >> 4) ^ (((lane & 15) >> 1) & 3)) << 3);

    int nt = K >> 5;
    // prologue: tiles 0 and 1 in flight; verify tile 0 landed (t1 still flying)
    STAGE_A(0, 0);  STAGE_B(0, 0);
    STAGE_A(1, 32); STAGE_B(1, 32);
    if constexpr (TL == 4) asm volatile("s_waitcnt vmcnt(4)" ::: "memory");
    else                   asm volatile("s_waitcnt vmcnt(3)" ::: "memory");
    __builtin_amdgcn_s_barrier();

    for (int t = 0; t < nt; ++t) {
        int cur = t % 3;
        int stg = (t + 2) % 3;
        bool dostage = (t + 2) < nt;
        int kk = (t + 2) << 5;
        const short* ab = &As[cur][0];
        const short* bb = &Bs[cur][0];

        // ---- phase 0: stage A(t+2) || read a[0..7], b[0..H-1] || MFMA half 1
        if (dostage) STAGE_A(stg, kk);
        bf16x8 a[8], b0[H];
#pragma unroll
        for (int m = 0; m < 8; ++m)
            a[m] = *(const bf16x8*)&ab[(rA + m * 16) * 32 + cswz];
#pragma unroll
        for (int n = 0; n < H; ++n)
            b0[n] = *(const bf16x8*)&bb[(rB + n * 16) * 32 + cswz];
        __builtin_amdgcn_s_setprio(1);
#pragma unroll
        for (int m = 0; m < 8; ++m)
#pragma unroll
            for (int n = 0; n < H; ++n)
                acc[m][n] = __builtin_amdgcn_mfma_f32_16x16x32_bf16(
                    a[m], b0[n], acc[m][n], 0, 0, 0);
        __builtin_amdgcn_s_setprio(0);
        __builtin_amdgcn_sched_barrier(0);
        __builtin_amdgcn_s_barrier();

        // ---- phase 1: stage B(t+2) || read b[H..NREP-1] || MFMA half 2
        if (dostage) STAGE_B(stg, kk);
        bf16x8 b1[H];
#pragma unroll
        for (int n = 0; n < H; ++n)
            b1[n] = *(const bf16x8*)&bb[(rB + (H + n) * 16) * 32 + cswz];
        __builtin_amdgcn_s_setprio(1);
#pragma unroll
        for (int m = 0; m < 8; ++m)
#pragma unroll
            for (int n = 0; n < H; ++n)
                acc[m][H + n] = __builtin_amdgcn_mfma_f32_16x16x32_bf16(
                    a[m], b1[n], acc[m][H + n], 0, 0, 0);
        __builtin_amdgcn_s_setprio(0);
        __builtin_amdgcn_sched_barrier(0);
        // once per tile: prove tile t+1 landed (t+2's TL loads may still fly)
        if (dostage) {
            if constexpr (TL == 4) asm volatile("s_waitcnt vmcnt(4)" ::: "memory");
            else                   asm volatile("s_waitcnt vmcnt(3)" ::: "memory");
        } else {
            asm volatile("s_waitcnt vmcnt(0)" ::: "memory");
        }
        __builtin_amdgcn_s_barrier();
    }
#undef STAGE_A
#undef STAGE_B

    // epilogue: C/D layout col=lane&15, row=(lane>>4)*4+reg
    int crow0 = brow + (wm << 7) + ((lane >> 4) << 2);
    int ccol0 = bcol + wn * NW + (lane & 15);
    float cs[NREP], cs2[NREP];
#pragma unroll
    for (int n = 0; n < NREP; ++n) { cs[n] = 0.f; cs2[n] = 0.f; }
#pragma unroll
    for (int m = 0; m < 8; ++m) {
#pragma unroll
        for (int n = 0; n < NREP; ++n) {
            int col = ccol0 + n * 16;
            float bv = bias[col];
#pragma unroll
            for (int r = 0; r < 4; ++r) {
                int row = crow0 + m * 16 + r;
                float v = acc[m][n][r] + bv;
                if (OUT_BF16) {
                    ((__hip_bfloat16*)Cout)[(size_t)row * N + col] = __float2bfloat16(v);
                } else {
                    ((float*)Cout)[(size_t)row * N + col] = v;
                }
                if (STATS) { cs[n] += v; cs2[n] += v * v; }
            }
        }
    }

    if (STATS) {
        // lanes {l, l+16, l+32, l+48} share a column within a wave
        float* sP = (float*)&As[0][0];   // [2][BN] sums + [2][BN] sumsq (4KB)
#pragma unroll
        for (int n = 0; n < NREP; ++n) {
            float s = cs[n], s2 = cs2[n];
            s  += __shfl_xor(s, 16);  s  += __shfl_xor(s, 32);
            s2 += __shfl_xor(s2, 16); s2 += __shfl_xor(s2, 32);
            if ((lane >> 4) == 0) {
                int c = wn * NW + n * 16 + (lane & 15);
                sP[wm * BN + c] = s;
                sP[2 * BN + wm * BN + c] = s2;
            }
        }
        __syncthreads();
        if (tid < BN) {
            float s  = sP[tid] + sP[BN + tid];
            float s2 = sP[2 * BN + tid] + sP[3 * BN + tid];
            pS [(size_t)bm * N + bcol + tid] = s;
            pS2[(size_t)bm * N + bcol + tid] = s2;
        }
    }
}

// ---------------------------------------------------------------------------
// BN stats reduce: 32 row-chunk partials -> per-column scale/shift
// ---------------------------------------------------------------------------
__global__ __launch_bounds__(256) void bn_stats2(
    const float* __restrict__ pS, const float* __restrict__ pS2,
    const float* __restrict__ g, const float* __restrict__ be,
    float* __restrict__ scale, float* __restrict__ shift, int ncols)
{
    int col = blockIdx.x * 256 + threadIdx.x;
    float s = 0.f, s2 = 0.f;
#pragma unroll
    for (int j = 0; j < 32; ++j) {
        s += pS[j * ncols + col];
        s2 += pS2[j * ncols + col];
    }
    float mu = s * (1.f / 8192.f);
    float var = s2 * (1.f / 8192.f) - mu * mu;
    float rs = rsqrtf(var + EPS);
    float sc = g[col] * rs;
    scale[col] = sc;
    shift[col] = be[col] - mu * sc;
}

// BN apply + ReLU, bf16 in -> bf16 out (hidden activation)
__global__ __launch_bounds__(256) void bn_apply_b2b(
    const short* __restrict__ t, const float* __restrict__ scale,
    const float* __restrict__ shift, short* __restrict__ out, int ncols)
{
    size_t i8 = (size_t)blockIdx.x * 256 + threadIdx.x;
    int col0 = (int)((i8 * 8) % ncols);
    bf16x8 v = ((const bf16x8*)t)[i8];
    bf16x8 o;
#pragma unroll
    for (int j = 0; j < 8; ++j) {
        float f = fmaxf(b2f(v[j]) * scale[col0 + j] + shift[col0 + j], 0.f);
        o[j] = f2b(f);
    }
    ((bf16x8*)out)[i8] = o;
}

// BN apply + ReLU, f32 in -> f32 out (final, in-place on d_out)
__global__ __launch_bounds__(256) void bn_apply_f32(
    const float* __restrict__ t, const float* __restrict__ scale,
    const float* __restrict__ shift, float* __restrict__ out, int ncols)
{
    size_t i4 = (size_t)blockIdx.x * 256 + threadIdx.x;
    int col0 = (int)((i4 * 4) % ncols);
    float4 v = ((const float4*)t)[i4];
    float4 o;
    o.x = fmaxf(v.x * scale[col0 + 0] + shift[col0 + 0], 0.f);
    o.y = fmaxf(v.y * scale[col0 + 1] + shift[col0 + 1], 0.f);
    o.z = fmaxf(v.z * scale[col0 + 2] + shift[col0 + 2], 0.f);
    o.w = fmaxf(v.w * scale[col0 + 3] + shift[col0 + 3], 0.f);
    ((float4*)out)[i4] = o;
}

// ---------------------------------------------------------------------------
extern "C" void kernel_launch(void* const* d_in, const int* in_sizes, int n_in,
                              void* d_out, int out_size, void* d_ws, size_t ws_size,
                              hipStream_t stream)
{
    const float* selfv = (const float*)d_in[0];   // [32,256,1024]
    const float* nbv   = (const float*)d_in[1];   // [32,256,8,2048]
    const float* mask  = (const float*)d_in[2];   // [32,256,8,1]
    const float* W_agg = (const float*)d_in[3];   // [3072,1024]
    const float* b_agg = (const float*)d_in[4];   // [1024]
    const float* W1    = (const float*)d_in[5];   // [1024,2048]
    const float* b1    = (const float*)d_in[6];   // [2048]
    const float* g1    = (const float*)d_in[7];
    const float* be1   = (const float*)d_in[8];
    const float* W2    = (const float*)d_in[9];   // [2048,1024]
    const float* b2    = (const float*)d_in[10];
    const float* g2    = (const float*)d_in[11];
    const float* be2   = (const float*)d_in[12];

    char* ws = (char*)d_ws;
    const size_t MiB = 1ull << 20;
    // layout (t1b aliases dead xb region; xb dead after GEMM1):
    __hip_bfloat16* h    = (__hip_bfloat16*)(ws + 0);          // [8192,1024] bf16, 16 MiB
    __hip_bfloat16* xb   = (__hip_bfloat16*)(ws + 16 * MiB);   // [8192,3072] bf16, 48 MiB
    __hip_bfloat16* t1b  = (__hip_bfloat16*)(ws + 16 * MiB);   // [8192,2048] bf16, 32 MiB
    __hip_bfloat16* h1   = (__hip_bfloat16*)(ws + 80 * MiB);   // [8192,2048] bf16, 32 MiB
    __hip_bfloat16* WaggT= (__hip_bfloat16*)(ws + 112 * MiB);  // [1024,3072] bf16, 6 MiB
    __hip_bfloat16* W1T  = (__hip_bfloat16*)(ws + 118 * MiB);  // [2048,1024] bf16, 4 MiB
    __hip_bfloat16* W2T  = (__hip_bfloat16*)(ws + 122 * MiB);  // [1024,2048] bf16, 4 MiB
    float* pS     = (float*)(ws + 126 * MiB);                   // [32,2048] partials
    float* pS2    = (float*)(ws + 126 * MiB + 512 * 1024);
    float* scale1 = (float*)(ws + 127 * MiB);
    float* shift1 = scale1 + 2048;
    float* scale2 = shift1 + 2048;
    float* shift2 = scale2 + 1024;

    // weight transposes (f32 -> bf16, K-major)
    wtrans<<<dim3(1024 / 32, 3072 / 32), 256, 0, stream>>>(W_agg, WaggT, 3072, 1024);
    wtrans<<<dim3(2048 / 32, 1024 / 32), 256, 0, stream>>>(W1, W1T, 1024, 2048);
    wtrans<<<dim3(1024 / 32, 2048 / 32), 256, 0, stream>>>(W2, W2T, 2048, 1024);

    // stage 1: masked mean + concat + bf16 cast
    build_x<<<ROWS, 256, 0, stream>>>(selfv, nbv, mask, xb);

    // GEMM1: h = x @ W_agg + b_agg   (bf16 out, no stats)  [grid 32x8 = 256]
    gemm256<128, 1, 0><<<(ROWS / 256) * (OUTC / 128), 512, 0, stream>>>(
        (const short*)xb, (const short*)WaggT, b_agg, h, nullptr, nullptr,
        ROWS, OUTC, XCOLS);

    // GEMM2: t1b = h @ W1 + b1   (bf16 out + BN1 partials)  [grid 32x8 = 256]
    gemm256<256, 1, 1><<<(ROWS / 256) * (HIDC / 256), 512, 0, stream>>>(
        (const short*)h, (const short*)W1T, b1, t1b, pS, pS2, ROWS, HIDC, OUTC);

    // BN1 reduce + apply + ReLU -> h1 (bf16)
    bn_stats2<<<HIDC / 256, 256, 0, stream>>>(pS, pS2, g1, be1, scale1, shift1, HIDC);
    bn_apply_b2b<<<(ROWS * HIDC) / 2048, 256, 0, stream>>>(
        (const short*)t1b, scale1, shift1, (short*)h1, HIDC);

    // GEMM3: d_out = h1 @ W2 + b2  (f32 out + BN2 partials) [grid 32x8 = 256]
    gemm256<128, 0, 1><<<(ROWS / 256) * (OUTC / 128), 512, 0, stream>>>(
        (const short*)h1, (const short*)W2T, b2, d_out, pS, pS2, ROWS, OUTC, HIDC);

    // BN2 reduce + apply + ReLU in-place on d_out
    bn_stats2<<<OUTC / 256, 256, 0, stream>>>(pS, pS2, g2, be2, scale2, shift2, OUTC);
    bn_apply_f32<<<(ROWS * OUTC) / 1024, 256, 0, stream>>>(
        (const float*)d_out, scale2, shift2, (float*)d_out, OUTC);
}

// Round 7
// 429.670 us; speedup vs baseline: 1.0918x; 1.0918x over previous
//
#include <hip/hip_runtime.h>
#include <hip/hip_bf16.h>

// Problem constants (B=32, N=256, K=8, D=1024, OUT=1024, HID=2048)
#define ROWS   8192      // B*N
#define DIM    1024      // D
#define XCOLS  3072      // 3*D
#define OUTC   1024
#define HIDC   2048
#define EPS    1e-5f

typedef __attribute__((ext_vector_type(8))) short bf16x8;   // 8 bf16 (4 VGPRs)
typedef __attribute__((ext_vector_type(4))) float f32x4;

#define GLOBAL_AS __attribute__((address_space(1)))
#define LDS_AS    __attribute__((address_space(3)))

__device__ __forceinline__ void gll16(const void* g, void* l) {
    // async global->LDS, 16B per lane; LDS dest = wave-uniform base + lane*16
    __builtin_amdgcn_global_load_lds((const GLOBAL_AS void*)g, (LDS_AS void*)l, 16, 0, 0);
}

__device__ __forceinline__ short f2b(float f) {
    __hip_bfloat16 h = __float2bfloat16(f);
    return *reinterpret_cast<short*>(&h);
}
__device__ __forceinline__ float b2f(short s) {
    unsigned u = ((unsigned)(unsigned short)s) << 16;
    return __uint_as_float(u);
}

// ---------------------------------------------------------------------------
// Stage 1: x[r, 0:1024] = self[r, :]; x[r, 1024:3072] = mean_k(nb[r,k,:]*mask[r,k])
// ---------------------------------------------------------------------------
__global__ __launch_bounds__(256) void build_x(
    const float* __restrict__ selfv, const float* __restrict__ nb,
    const float* __restrict__ mask, __hip_bfloat16* __restrict__ xb)
{
    int r = blockIdx.x;
    int tid = threadIdx.x;
    __shared__ float ms[8];
    if (tid < 8) ms[tid] = mask[r * 8 + tid];
    __syncthreads();

    __hip_bfloat16* xr = xb + (size_t)r * XCOLS;

    {
        float4 v = ((const float4*)(selfv + (size_t)r * DIM))[tid];
        short4 o;
        o.x = f2b(v.x); o.y = f2b(v.y); o.z = f2b(v.z); o.w = f2b(v.w);
        *(short4*)&xr[tid * 4] = o;
    }

    const float4* nbase = (const float4*)(nb + (size_t)r * 8 * 2048);
#pragma unroll
    for (int half = 0; half < 2; ++half) {
        int c4 = half * 256 + tid;
        float4 acc = make_float4(0.f, 0.f, 0.f, 0.f);
#pragma unroll
        for (int k = 0; k < 8; ++k) {
            float4 t = nbase[k * 512 + c4];
            float m = ms[k];
            acc.x += t.x * m; acc.y += t.y * m; acc.z += t.z * m; acc.w += t.w * m;
        }
        short4 o;
        o.x = f2b(acc.x * 0.125f); o.y = f2b(acc.y * 0.125f);
        o.z = f2b(acc.z * 0.125f); o.w = f2b(acc.w * 0.125f);
        *(short4*)&xr[1024 + c4 * 4] = o;
    }
}

// ---------------------------------------------------------------------------
// Fused weight transposes (one launch): W[K][N] f32 -> Wt[N][K] bf16, x3
// ---------------------------------------------------------------------------
__global__ __launch_bounds__(256) void wtrans3(
    const float* __restrict__ Wa, __hip_bfloat16* __restrict__ WaT,
    const float* __restrict__ W1, __hip_bfloat16* __restrict__ W1T,
    const float* __restrict__ W2, __hip_bfloat16* __restrict__ W2T)
{
    // segment 0: 3072x1024 (3072 blocks) | 1: 1024x2048 (2048) | 2: 2048x1024 (2048)
    int b = blockIdx.x;
    const float* W; __hip_bfloat16* Wt; int K, N;
    if (b < 3072)      { W = Wa; Wt = WaT; K = 3072; N = 1024; }
    else if (b < 5120) { W = W1; Wt = W1T; K = 1024; N = 2048; b -= 3072; }
    else               { W = W2; Wt = W2T; K = 2048; N = 1024; b -= 5120; }
    int nxb = N >> 5;
    int n0 = (b % nxb) << 5, k0 = (b / nxb) << 5;

    __shared__ float t[32][33];
    int tx = threadIdx.x & 31, ty = threadIdx.x >> 5;   // 32 x 8
#pragma unroll
    for (int i = 0; i < 4; ++i)
        t[ty + i * 8][tx] = W[(size_t)(k0 + ty + i * 8) * N + n0 + tx];
    __syncthreads();
#pragma unroll
    for (int i = 0; i < 4; ++i) {
        int n = ty + i * 8;
        Wt[(size_t)(n0 + n) * K + k0 + tx] = __float2bfloat16(t[tx][n]);
    }
}

// ---------------------------------------------------------------------------
// GEMM: C[M,N] = A[M,K] @ Bt[N,K]^T + bias   (bf16 in, f32 acc)
// 128x128 tile, BK=32, 4 waves (2x2), 16x16x32 MFMA.
// 3-buffer pipeline, counted vmcnt (T4): tiles i..i+2 in flight; per K-step:
// vmcnt(8) -> s_barrier -> ds_read+MFMA (setprio) -> s_barrier -> stage i+3.
// Persistent over output tiles: block processes ntiles/gridDim tiles
// (uniform trip count -> no ragged dispatch rounds).
// OUT_BF16: 1 -> bf16 C, 0 -> f32 C.
// STATS: per-block-row column partials (sum,sumsq incl. bias) -> pS/pS2[bm][col]
// ---------------------------------------------------------------------------
template <int OUT_BF16, int STATS>
__global__ __launch_bounds__(256) void gemm_bt(
    const short* __restrict__ A, const short* __restrict__ Bt,
    const float* __restrict__ bias, void* __restrict__ Cout,
    float* __restrict__ pS, float* __restrict__ pS2,
    int M, int N, int K, int ntiles)
{
    __shared__ short As[3][128 * 32];   // 3 x 8 KB
    __shared__ short Bs[3][128 * 32];   // 3 x 8 KB   (48 KB total)

    int tid = threadIdx.x;
    int lane = tid & 63;
    int w = tid >> 6;
    int wm = w >> 1, wn = w & 1;

    int nbn = N >> 7;
    int rowa = (wm << 6) + (lane & 15);
    int rowb = (wn << 6) + (lane & 15);
    int kc = (lane >> 4) << 3;
    int lofs = w << 9;
    short* asb = &As[0][0];
    short* bsb = &Bs[0][0];
    int s0 = tid, s1 = tid + 256;

    for (int tix = blockIdx.x; tix < ntiles; tix += gridDim.x) {
        // XCD swizzle on tile index (ntiles % 8 == 0 here)
        int swz = (tix & 7) * (ntiles >> 3) + (tix >> 3);
        int bm = swz / nbn, bn = swz % nbn;
        int brow = bm << 7, bcol = bn << 7;

        f32x4 acc[4][4] = {};

        const short* gA0 = A + (size_t)(brow + (s0 >> 2)) * K + ((s0 & 3) << 3);
        const short* gA1 = A + (size_t)(brow + (s1 >> 2)) * K + ((s1 & 3) << 3);
        const short* gB0 = Bt + (size_t)(bcol + (s0 >> 2)) * K + ((s0 & 3) << 3);
        const short* gB1 = Bt + (size_t)(bcol + (s1 >> 2)) * K + ((s1 & 3) << 3);

#define STAGE(ab, bb, kk)                       \
    do {                                        \
        gll16(gA0 + (kk), (ab) + lofs);         \
        gll16(gA1 + (kk), (ab) + 2048 + lofs);  \
        gll16(gB0 + (kk), (bb) + lofs);         \
        gll16(gB1 + (kk), (bb) + 2048 + lofs);  \
    } while (0)

#define KSTEP(ab, bb, VM, DOSTAGE, KKN)                                    \
    do {                                                                   \
        asm volatile("s_waitcnt vmcnt(" VM ")" ::: "memory");              \
        __builtin_amdgcn_s_barrier();                                      \
        __builtin_amdgcn_sched_barrier(0);                                 \
        bf16x8 a[4], b[4];                                                 \
        _Pragma("unroll")                                                  \
        for (int m = 0; m < 4; ++m)                                        \
            a[m] = *(const bf16x8*)&(ab)[((rowa + (m << 4)) << 5) + kc];   \
        _Pragma("unroll")                                                  \
        for (int n = 0; n < 4; ++n)                                        \
            b[n] = *(const bf16x8*)&(bb)[((rowb + (n << 4)) << 5) + kc];   \
        __builtin_amdgcn_s_setprio(1);                                     \
        _Pragma("unroll")                                                  \
        for (int m = 0; m < 4; ++m) {                                      \
            _Pragma("unroll")                                              \
            for (int n = 0; n < 4; ++n)                                    \
                acc[m][n] = __builtin_amdgcn_mfma_f32_16x16x32_bf16(       \
                    a[m], b[n], acc[m][n], 0, 0, 0);                       \
        }                                                                  \
        __builtin_amdgcn_s_setprio(0);                                     \
        __builtin_amdgcn_sched_barrier(0);                                 \
        __builtin_amdgcn_s_barrier();                                      \
        if (DOSTAGE) STAGE(ab, bb, KKN);                                   \
    } while (0)

        int nk = K >> 5;               // 32 / 64 / 96 here (always >= 3)

        STAGE(asb,        bsb,        0);
        STAGE(asb + 4096, bsb + 4096, 32);
        STAGE(asb + 8192, bsb + 8192, 64);

        int p = 0;
        for (int i = 0; i < nk - 2; ++i) {
            short* ab = asb + (p << 12);
            short* bb = bsb + (p << 12);
            KSTEP(ab, bb, "8", (i + 3 < nk), ((i + 3) << 5));
            p = (p == 2) ? 0 : p + 1;
        }
        {   // tail: tiles nk-2 (wait to 4) and nk-1 (wait to 0)
            short* ab = asb + (p << 12);
            short* bb = bsb + (p << 12);
            KSTEP(ab, bb, "4", 0, 0);
            p = (p == 2) ? 0 : p + 1;
            ab = asb + (p << 12);
            bb = bsb + (p << 12);
            KSTEP(ab, bb, "0", 0, 0);
        }
#undef KSTEP
#undef STAGE

        // epilogue: C/D layout col=lane&15, row=(lane>>4)*4+reg
        int crow0 = brow + (wm << 6) + ((lane >> 4) << 2);
        int ccol0 = bcol + (wn << 6) + (lane & 15);
        float cs[4] = {0.f, 0.f, 0.f, 0.f}, cs2[4] = {0.f, 0.f, 0.f, 0.f};
#pragma unroll
        for (int m = 0; m < 4; ++m) {
#pragma unroll
            for (int n = 0; n < 4; ++n) {
                int col = ccol0 + n * 16;
                float bv = bias[col];
#pragma unroll
                for (int r = 0; r < 4; ++r) {
                    int row = crow0 + m * 16 + r;
                    float v = acc[m][n][r] + bv;
                    if (OUT_BF16) {
                        ((__hip_bfloat16*)Cout)[(size_t)row * N + col] = __float2bfloat16(v);
                    } else {
                        ((float*)Cout)[(size_t)row * N + col] = v;
                    }
                    if (STATS) { cs[n] += v; cs2[n] += v * v; }
                }
            }
        }

        if (STATS) {
            float* sP = (float*)&As[0][0];   // reuse LDS (fenced by loop barrier)
#pragma unroll
            for (int n = 0; n < 4; ++n) {
                float s = cs[n], s2 = cs2[n];
                s  += __shfl_xor(s, 16);  s  += __shfl_xor(s, 32);
                s2 += __shfl_xor(s2, 16); s2 += __shfl_xor(s2, 32);
                if ((lane >> 4) == 0) {
                    int c = (wn << 6) + (n << 4) + (lane & 15);
                    sP[wm * 128 + c] = s;
                    sP[256 + wm * 128 + c] = s2;
                }
            }
            __syncthreads();
            if (tid < 128) {
                float s = sP[tid] + sP[128 + tid];
                float s2 = sP[256 + tid] + sP[384 + tid];
                pS [(size_t)bm * N + bcol + tid] = s;
                pS2[(size_t)bm * N + bcol + tid] = s2;
            }
            __syncthreads();   // protect sP before next tile's STAGE
        }
    }
}

// ---------------------------------------------------------------------------
// BN stats reduce: 64 row-chunk partials -> per-column scale/shift
// ---------------------------------------------------------------------------
__global__ __launch_bounds__(256) void bn_stats2(
    const float* __restrict__ pS, const float* __restrict__ pS2,
    const float* __restrict__ g, const float* __restrict__ be,
    float* __restrict__ scale, float* __restrict__ shift, int ncols)
{
    int col = blockIdx.x * 256 + threadIdx.x;
    float s = 0.f, s2 = 0.f;
#pragma unroll
    for (int j = 0; j < 64; ++j) {
        s += pS[j * ncols + col];
        s2 += pS2[j * ncols + col];
    }
    float mu = s * (1.f / 8192.f);
    float var = s2 * (1.f / 8192.f) - mu * mu;
    float rs = rsqrtf(var + EPS);
    float sc = g[col] * rs;
    scale[col] = sc;
    shift[col] = be[col] - mu * sc;
}

// BN apply + ReLU, bf16 in -> bf16 out (hidden activation)
__global__ __launch_bounds__(256) void bn_apply_b2b(
    const short* __restrict__ t, const float* __restrict__ scale,
    const float* __restrict__ shift, short* __restrict__ out, int ncols)
{
    size_t i8 = (size_t)blockIdx.x * 256 + threadIdx.x;
    int col0 = (int)((i8 * 8) % ncols);
    bf16x8 v = ((const bf16x8*)t)[i8];
    bf16x8 o;
#pragma unroll
    for (int j = 0; j < 8; ++j) {
        float f = fmaxf(b2f(v[j]) * scale[col0 + j] + shift[col0 + j], 0.f);
        o[j] = f2b(f);
    }
    ((bf16x8*)out)[i8] = o;
}

// BN apply + ReLU, bf16 in -> f32 out (final, into d_out)
__global__ __launch_bounds__(256) void bn_apply_b2f(
    const short* __restrict__ t, const float* __restrict__ scale,
    const float* __restrict__ shift, float* __restrict__ out, int ncols)
{
    size_t i8 = (size_t)blockIdx.x * 256 + threadIdx.x;
    int col0 = (int)((i8 * 8) % ncols);
    bf16x8 v = ((const bf16x8*)t)[i8];
    float4 o0, o1;
    o0.x = fmaxf(b2f(v[0]) * scale[col0 + 0] + shift[col0 + 0], 0.f);
    o0.y = fmaxf(b2f(v[1]) * scale[col0 + 1] + shift[col0 + 1], 0.f);
    o0.z = fmaxf(b2f(v[2]) * scale[col0 + 2] + shift[col0 + 2], 0.f);
    o0.w = fmaxf(b2f(v[3]) * scale[col0 + 3] + shift[col0 + 3], 0.f);
    o1.x = fmaxf(b2f(v[4]) * scale[col0 + 4] + shift[col0 + 4], 0.f);
    o1.y = fmaxf(b2f(v[5]) * scale[col0 + 5] + shift[col0 + 5], 0.f);
    o1.z = fmaxf(b2f(v[6]) * scale[col0 + 6] + shift[col0 + 6], 0.f);
    o1.w = fmaxf(b2f(v[7]) * scale[col0 + 7] + shift[col0 + 7], 0.f);
    ((float4*)out)[i8 * 2]     = o0;
    ((float4*)out)[i8 * 2 + 1] = o1;
}

// ---------------------------------------------------------------------------
extern "C" void kernel_launch(void* const* d_in, const int* in_sizes, int n_in,
                              void* d_out, int out_size, void* d_ws, size_t ws_size,
                              hipStream_t stream)
{
    const float* selfv = (const float*)d_in[0];   // [32,256,1024]
    const float* nbv   = (const float*)d_in[1];   // [32,256,8,2048]
    const float* mask  = (const float*)d_in[2];   // [32,256,8,1]
    const float* W_agg = (const float*)d_in[3];   // [3072,1024]
    const float* b_agg = (const float*)d_in[4];   // [1024]
    const float* W1    = (const float*)d_in[5];   // [1024,2048]
    const float* b1    = (const float*)d_in[6];   // [2048]
    const float* g1    = (const float*)d_in[7];
    const float* be1   = (const float*)d_in[8];
    const float* W2    = (const float*)d_in[9];   // [2048,1024]
    const float* b2    = (const float*)d_in[10];
    const float* g2    = (const float*)d_in[11];
    const float* be2   = (const float*)d_in[12];

    char* ws = (char*)d_ws;
    const size_t MiB = 1ull << 20;
    // layout (t1b aliases dead xb region; xb dead after GEMM1; h reused as t2b):
    __hip_bfloat16* h    = (__hip_bfloat16*)(ws + 0);          // [8192,1024] bf16, 16 MiB
    __hip_bfloat16* xb   = (__hip_bfloat16*)(ws + 16 * MiB);   // [8192,3072] bf16, 48 MiB
    __hip_bfloat16* t1b  = (__hip_bfloat16*)(ws + 16 * MiB);   // [8192,2048] bf16, 32 MiB
    __hip_bfloat16* h1   = (__hip_bfloat16*)(ws + 80 * MiB);   // [8192,2048] bf16, 32 MiB
    __hip_bfloat16* WaggT= (__hip_bfloat16*)(ws + 112 * MiB);  // [1024,3072] bf16, 6 MiB
    __hip_bfloat16* W1T  = (__hip_bfloat16*)(ws + 118 * MiB);  // [2048,1024] bf16, 4 MiB
    __hip_bfloat16* W2T  = (__hip_bfloat16*)(ws + 122 * MiB);  // [1024,2048] bf16, 4 MiB
    float* pS     = (float*)(ws + 126 * MiB);                   // [64,2048] partials
    float* pS2    = (float*)(ws + 126 * MiB + 512 * 1024);
    float* scale1 = (float*)(ws + 127 * MiB);
    float* shift1 = scale1 + 2048;
    float* scale2 = shift1 + 2048;
    float* shift2 = scale2 + 1024;
    __hip_bfloat16* t2b = h;   // [8192,1024] bf16 (h is dead after GEMM2)

    // fused weight transposes (f32 -> bf16, K-major), one launch
    wtrans3<<<7168, 256, 0, stream>>>(W_agg, WaggT, W1, W1T, W2, W2T);

    // stage 1: masked mean + concat + bf16 cast
    build_x<<<ROWS, 256, 0, stream>>>(selfv, nbv, mask, xb);

    // GEMM1: h = x @ W_agg + b_agg   (bf16 out, no stats)  [512 tiles, 1/block]
    gemm_bt<1, 0><<<512, 256, 0, stream>>>(
        (const short*)xb, (const short*)WaggT, b_agg, h, nullptr, nullptr,
        ROWS, OUTC, XCOLS, 512);

    // GEMM2: t1b = h @ W1 + b1  (bf16 out + BN1 partials)  [1024 tiles, 2/block]
    gemm_bt<1, 1><<<512, 256, 0, stream>>>(
        (const short*)h, (const short*)W1T, b1, t1b, pS, pS2, ROWS, HIDC, OUTC, 1024);

    // BN1 reduce + apply + ReLU -> h1 (bf16)
    bn_stats2<<<HIDC / 256, 256, 0, stream>>>(pS, pS2, g1, be1, scale1, shift1, HIDC);
    bn_apply_b2b<<<(ROWS * HIDC) / 2048, 256, 0, stream>>>(
        (const short*)t1b, scale1, shift1, (short*)h1, HIDC);

    // GEMM3: t2b = h1 @ W2 + b2  (bf16 out + BN2 partials) [512 tiles, 1/block]
    gemm_bt<1, 1><<<512, 256, 0, stream>>>(
        (const short*)h1, (const short*)W2T, b2, t2b, pS, pS2, ROWS, OUTC, HIDC, 512);

    // BN2 reduce + apply + ReLU -> d_out (f32)
    bn_stats2<<<OUTC / 256, 256, 0, stream>>>(pS, pS2, g2, be2, scale2, shift2, OUTC);
    bn_apply_b2f<<<(ROWS * OUTC) / 2048, 256, 0, stream>>>(
        (const short*)t2b, scale2, shift2, (float*)d_out, OUTC);
}